// Round 6
// baseline (590.656 us; speedup 1.0000x reference)
//
#include <hip/hip_runtime.h>

// ---------------- workspace layout (float offsets) ----------------
#define AFF_OFF   0u         // [2][1024 p][1024 q]
#define XC_OFF    2097152u   // [2][1024 p][1024 q]
#define K8_OFF    4194304u   // Ktab8 [81 cls][125 item][8] (pad cols 5..7 = 0)
#define BIAS_OFF  4275328u   // [32 l][3 cd][3 ch][3 cw]
#define PART_OFF  4276224u   // topq partials [2][32][3][1024]
#define CNT_OFF   4472832u   // atomic counter (1 uint)
#define ZP_OFF    4476928u   // zero page (1024 floats)
// total 4477952 floats = 17.9 MB

#define SLOT 2160            // ring-slot stride (floats); 5 slots
#define KVQ_OFF 10800        // kv tables inside LDS: [int f4 500][bnd f4 500][int t4 125][bnd t4 125]

static __device__ __forceinline__ int imax(int a, int b){ return a > b ? a : b; }
static __device__ __forceinline__ int imin(int a, int b){ return a < b ? a : b; }

static __device__ __forceinline__ void ins3(float& a0, float& a1, float& a2, float v){
  if (v > a0){ a2 = a1; a1 = a0; a0 = v; }
  else if (v > a1){ a2 = a1; a1 = v; }
  else if (v > a2){ a2 = v; }
}

static __device__ __forceinline__ void fma40(const float4 fa, const float4 fb, const float4 fc,
                                             const float4 kq, const float k4, float* acc){
  acc[0] = fmaf(kq.x, fa.x, acc[0]); acc[0] = fmaf(kq.y, fa.y, acc[0]);
  acc[0] = fmaf(kq.z, fa.z, acc[0]); acc[0] = fmaf(kq.w, fa.w, acc[0]);
  acc[0] = fmaf(k4,  fb.x, acc[0]);
  acc[1] = fmaf(kq.x, fa.y, acc[1]); acc[1] = fmaf(kq.y, fa.z, acc[1]);
  acc[1] = fmaf(kq.z, fa.w, acc[1]); acc[1] = fmaf(kq.w, fb.x, acc[1]);
  acc[1] = fmaf(k4,  fb.y, acc[1]);
  acc[2] = fmaf(kq.x, fa.z, acc[2]); acc[2] = fmaf(kq.y, fa.w, acc[2]);
  acc[2] = fmaf(kq.z, fb.x, acc[2]); acc[2] = fmaf(kq.w, fb.y, acc[2]);
  acc[2] = fmaf(k4,  fb.z, acc[2]);
  acc[3] = fmaf(kq.x, fa.w, acc[3]); acc[3] = fmaf(kq.y, fb.x, acc[3]);
  acc[3] = fmaf(kq.z, fb.y, acc[3]); acc[3] = fmaf(kq.w, fb.z, acc[3]);
  acc[3] = fmaf(k4,  fb.w, acc[3]);
  acc[4] = fmaf(kq.x, fb.x, acc[4]); acc[4] = fmaf(kq.y, fb.y, acc[4]);
  acc[4] = fmaf(kq.z, fb.z, acc[4]); acc[4] = fmaf(kq.w, fb.w, acc[4]);
  acc[4] = fmaf(k4,  fc.x, acc[4]);
  acc[5] = fmaf(kq.x, fb.y, acc[5]); acc[5] = fmaf(kq.y, fb.z, acc[5]);
  acc[5] = fmaf(kq.z, fb.w, acc[5]); acc[5] = fmaf(kq.w, fc.x, acc[5]);
  acc[5] = fmaf(k4,  fc.y, acc[5]);
  acc[6] = fmaf(kq.x, fb.z, acc[6]); acc[6] = fmaf(kq.y, fb.w, acc[6]);
  acc[6] = fmaf(kq.z, fc.x, acc[6]); acc[6] = fmaf(kq.w, fc.y, acc[6]);
  acc[6] = fmaf(k4,  fc.z, acc[6]);
  acc[7] = fmaf(kq.x, fb.w, acc[7]); acc[7] = fmaf(kq.y, fc.x, acc[7]);
  acc[7] = fmaf(kq.z, fc.y, acc[7]); acc[7] = fmaf(kq.w, fc.z, acc[7]);
  acc[7] = fmaf(k4,  fc.w, acc[7]);
}

#define GLL4(gsrc, ldst) __builtin_amdgcn_global_load_lds( \
    (const __attribute__((address_space(1))) void*)(gsrc), \
    (__attribute__((address_space(3))) void*)(ldst), 4, 0, 0)

// ============ K1: fused { gemm(+norms) | tab | counter init } ============
__global__ __launch_bounds__(256) void prep_k(const float* __restrict__ xp,
                                              const float* __restrict__ xq,
                                              const float* __restrict__ W1,
                                              const float* __restrict__ B1,
                                              const float* __restrict__ W2,
                                              const float* __restrict__ B2,
                                              float* __restrict__ ws){
  __shared__ __align__(16) float shbuf[4096];    // gemm: As/Bs dbuf; tab: sW1/sW2
  int bid0 = blockIdx.x;
  int t = threadIdx.x;

  if (bid0 >= 512){
    // ---------------- tab part (324 blocks) ----------------
    if (bid0 == 512 && t == 0) *(unsigned*)(ws + CNT_OFF) = 0u;
    float* sW1 = shbuf;
    float* sW2 = shbuf + 1296;
    for (int i = t; i < 1296; i += 256){ sW1[i] = W1[i]; sW2[i] = W2[i]; }
    __syncthreads();
    int tid = (bid0 - 512) * 256 + t;
    if (tid < 50625){
      int c = tid / 625, r = tid % 625;
      int cw = c % 3, ch = (c / 3) % 3, cd = (c / 9) % 3, cl = c / 27;
      int rw = r % 5, rh = (r / 5) % 5, rd = (r / 25) % 5, rl = r / 125;
      int al0 = imax(0, rl - 2), al1 = imin(2, rl);
      if (cl == 0) al0 = imax(al0, 1);
      if (cl == 2) al1 = imin(al1, 1);
      int ad0 = imax(0, rd - 2), ad1 = imin(2, rd);
      if (cd == 0) ad0 = imax(ad0, 1);
      if (cd == 2) ad1 = imin(ad1, 1);
      int ah0 = imax(0, rh - 2), ah1 = imin(2, rh);
      if (ch == 0) ah0 = imax(ah0, 1);
      if (ch == 2) ah1 = imin(ah1, 1);
      int aw0 = imax(0, rw - 2), aw1 = imin(2, rw);
      if (cw == 0) aw0 = imax(aw0, 1);
      if (cw == 2) aw1 = imin(aw1, 1);
      float s = 0.f;
      for (int a = al0; a <= al1; ++a)
        for (int bq = ad0; bq <= ad1; ++bq)
          for (int cq = ah0; cq <= ah1; ++cq)
            for (int dq = aw0; dq <= aw1; ++dq){
              int q2 = ((a * 3 + bq) * 3 + cq) * 3 + dq;
              int q1 = (((rl - a) * 3 + (rd - bq)) * 3 + (rh - cq)) * 3 + (rw - dq);
              for (int co = 0; co < 16; ++co)
                s += sW2[co * 81 + q2] * sW1[co * 81 + q1];
            }
      int item = (r * 205) >> 10;           // r/5
      int j = r - item * 5;
      ws[K8_OFF + (size_t)c * 1000 + item * 8 + j] = s;
    } else if (tid < 51489){
      int t2 = tid - 50625;
      int l = t2 / 27, rest = t2 % 27;
      int cd = rest / 9, ch = (rest / 3) % 3, cw = rest % 3;
      float v = 0.f;
      for (int i = 0; i < 3; ++i){ int y = l + i - 1; if (y >= 0 && y < 32) v += B2[i]; }
      int jlo = (cd == 0) ? 1 : 0, jhi = (cd == 2) ? 1 : 2;
      int klo = (ch == 0) ? 1 : 0, khi = (ch == 2) ? 1 : 2;
      int mlo = (cw == 0) ? 1 : 0, mhi = (cw == 2) ? 1 : 2;
      for (int i = 0; i < 3; ++i){
        int y = l + i - 1; if (y < 0 || y >= 32) continue;
        for (int co = 0; co < 16; ++co){
          float b1e = 0.f;
          for (int i2 = 0; i2 < 3; ++i2){
            int y2 = y + i2 - 1; if (y2 >= 0 && y2 < 32) b1e += B1[i2 * 16 + co];
          }
          float S = 0.f;
          for (int j = jlo; j <= jhi; ++j)
            for (int k = klo; k <= khi; ++k)
              for (int m = mlo; m <= mhi; ++m)
                S += sW2[co * 81 + ((i * 3 + j) * 3 + k) * 3 + m];
          v += b1e * S;
        }
      }
      ws[BIAS_OFF + t2] = v;
    } else if (tid < 52513){
      ws[ZP_OFF + (tid - 51489)] = 0.f;                 // zero page
    } else if (tid < 82888){
      int u = tid - 52513;                              // pad cols 5..7 of Ktab8
      int c = u / 375, r2 = u % 375;
      int item = r2 / 3, j = 5 + r2 % 3;
      ws[K8_OFF + (size_t)c * 1000 + item * 8 + j] = 0.f;
    }
    return;
  }

  // ---------------- gemm part (512 blocks), norms fused ----------------
  int bid = (bid0 & 7) * 64 + (bid0 >> 3);    // XCD swizzle (512 % 8 == 0)
  int qi = bid & 15, pi = (bid >> 4) & 15, b = bid >> 8;
  const float* A = xp + (size_t)b * 262144;   // [c][p]
  const float* B = xq + (size_t)b * 262144;   // [c][q]
  float* C = ws + AFF_OFF + (size_t)b * 1048576;
  int tx = t & 15, ty = t >> 4;
  int row = t >> 4, col = (t & 15) * 4;
  float* As0 = shbuf;            // [16][64]
  float* As1 = shbuf + 1024;
  float* Bs0 = shbuf + 2048;
  float* Bs1 = shbuf + 3072;
  const float* Ag = A + (size_t)row * 1024 + pi * 64 + col;
  const float* Bg = B + (size_t)row * 1024 + qi * 64 + col;
  float4 ra = *(const float4*)Ag;
  float4 rb = *(const float4*)Bg;
  *(float4*)&As0[row * 64 + col] = ra;
  *(float4*)&Bs0[row * 64 + col] = rb;
  __syncthreads();
  float acc[4][4] = {};
  float na[4] = {}, nb[4] = {};
  const float* Asc = As0; const float* Bsc = Bs0;
  float* Asn = As1; float* Bsn = Bs1;
  for (int k0 = 16; k0 <= 256; k0 += 16){
    if (k0 < 256){
      ra = *(const float4*)(Ag + (size_t)k0 * 1024);
      rb = *(const float4*)(Bg + (size_t)k0 * 1024);
    }
    #pragma unroll
    for (int kk = 0; kk < 16; ++kk){
      float4 av = *(const float4*)&Asc[kk * 64 + ty * 4];
      float4 bv = *(const float4*)&Bsc[kk * 64 + tx * 4];
      float a4[4] = {av.x, av.y, av.z, av.w};
      float b4[4] = {bv.x, bv.y, bv.z, bv.w};
      #pragma unroll
      for (int i = 0; i < 4; ++i){
        na[i] = fmaf(a4[i], a4[i], na[i]);
        nb[i] = fmaf(b4[i], b4[i], nb[i]);
        #pragma unroll
        for (int j = 0; j < 4; ++j)
          acc[i][j] = fmaf(a4[i], b4[j], acc[i][j]);
      }
    }
    if (k0 < 256){
      *(float4*)&Asn[row * 64 + col] = ra;
      *(float4*)&Bsn[row * 64 + col] = rb;
      __syncthreads();
      float* tmp;
      tmp = (float*)Asc; Asc = Asn; Asn = tmp;
      tmp = (float*)Bsc; Bsc = Bsn; Bsn = tmp;
    }
  }
  float iva[4], ivb[4];
  #pragma unroll
  for (int i = 0; i < 4; ++i){
    iva[i] = 1.0f / fmaxf(sqrtf(na[i]), 1e-12f);
    ivb[i] = 1.0f / fmaxf(sqrtf(nb[i]), 1e-12f);
  }
  #pragma unroll
  for (int i = 0; i < 4; ++i){
    float4 v = make_float4(acc[i][0] * iva[i] * ivb[0], acc[i][1] * iva[i] * ivb[1],
                           acc[i][2] * iva[i] * ivb[2], acc[i][3] * iva[i] * ivb[3]);
    *(float4*)&C[(size_t)(pi * 64 + ty * 4 + i) * 1024 + qi * 64 + tx * 4] = v;
  }
}

// ============ K2: composed 5^4 conv, d-streamed, split kv tables in LDS ============
__global__ __launch_bounds__(256, 3) void conv_k(float* __restrict__ ws){
  __shared__ __align__(16) float slots[5 * SLOT + 1250];   // 12050 f = 48.2 KB -> 3 blocks/CU

  int bid0 = blockIdx.x;
  int bid = (bid0 & 7) * 128 + (bid0 >> 3);       // XCD swizzle (1024 % 8 == 0)
  int dq = bid & 3, hq = (bid >> 2) & 3, l0 = (bid >> 4) & 31, b = bid >> 9;
  int h0 = hq * 8, dstart = dq * 8;
  int t = threadIdx.x;
  const float* affB = ws + AFF_OFF + (size_t)b * 1048576;
  float* xc = ws + XC_OFF + (size_t)b * 1048576;
  const float* K8G = ws + K8_OFF;
  const float* bias = ws + BIAS_OFF;
  const float* zp = ws + ZP_OFF;

  int cl = (l0 == 0) ? 0 : (l0 == 31) ? 2 : 1;
  int chB = (hq == 0) ? 0 : (hq == 3) ? 2 : 1;    // boundary-row h class (1 if none)

  // A-phase lane constants: t = wv(2b) | sl(3b) | hsel(1b) | oct(2b)
  int wv = t >> 6, u3 = t & 7;
  int oct = u3 & 3, hsel = u3 >> 2, hl = wv * 2 + hsel;
  int hA = h0 + hl;
  int chA = (hA == 0) ? 0 : (hA == 31) ? 2 : 1;
  int sl = (t >> 3) & 7;
  int dl0s = (sl >= 5) ? 1 : 0;
  int dh0s = sl - 5 * dl0s;
  bool isBnd = (hq == 0 && hl == 0) || (hq == 3 && hl == 7);
  int bndoff4 = isBnd ? 500 : 0;
  int bndoff1 = isBnd ? 125 : 0;

  // B-phase lane constants
  int outB = t >> 4, subB = t & 15;
  int hlB = outB >> 1, wx31 = outB & 1;
  int hB = h0 + hlB;
  int chB2 = (hB == 0) ? 0 : (hB == 31) ? 2 : 1;
  int cwB = wx31 ? 2 : 0;
  int wofB = wx31 ? 28 : 0;

  // staging global offsets (9 rounds x 256 lanes = 2160 floats/plane)
  int o0, o1, o2, o3, o4, o5, o6, o7, o8;
#define PRE(r) { int flat = (r)*256 + t; \
    int wi = flat % 36; int rest = flat / 36; int hi = rest % 12; int dl2 = rest / 12; \
    int lp_ = l0 + dl2 - 2, hp_ = h0 + hi - 2, wp_ = wi - 2; \
    bool ok = ((unsigned)lp_ < 32u) && ((unsigned)hp_ < 32u) && ((unsigned)wp_ < 32u); \
    o##r = ok ? (lp_ * 32768 + hp_ * 32 + wp_) : -1; }
  PRE(0) PRE(1) PRE(2) PRE(3) PRE(4) PRE(5) PRE(6) PRE(7) PRE(8)
#undef PRE

#define STG(r, sp_) { const float* s_ = (pOK_ && o##r >= 0) ? (affB + o##r + dpo_) : zp; \
    GLL4(s_, sp_ + (r)*256 + t); }
#define STAGE(si_, dpv_) do { \
    int dp_ = (dpv_); bool pOK_ = ((unsigned)dp_ < 32u); int dpo_ = dp_ * 1024; \
    float* sp_ = slots + (si_) * SLOT; \
    STG(0, sp_) STG(1, sp_) STG(2, sp_) STG(3, sp_) \
    STG(4, sp_) STG(5, sp_) STG(6, sp_) STG(7, sp_) \
    if (t < 112) sp_[2048 + t] = (pOK_ && o8 >= 0) ? affB[o8 + dpo_] : 0.f; \
  } while (0)

  // kv tables: entries in traversal order u=0..124 (u<25: dd=0 f=dl*5+dh; u>=25: g=u-25,
  // dd=1+g/25, dl=(g%25)/5, dh=g%5); m = dl*25+dd*5+dh indexes K8G [125][8].
#define LOADKV(cdv_) do { int cd_ = (cdv_); \
    int clsI_ = ((cl * 3 + cd_) * 3 + 1) * 3 + 1; \
    int clsB_ = ((cl * 3 + cd_) * 3 + chB) * 3 + 1; \
    for (int r_ = 0; r_ < 5; ++r_){ \
      int i_ = r_ * 256 + t; \
      if (i_ < 1250){ \
        int u_, j_, cls_; \
        if (i_ < 500){ u_ = i_ >> 2; j_ = i_ & 3; cls_ = clsI_; } \
        else if (i_ < 1000){ u_ = (i_ - 500) >> 2; j_ = i_ & 3; cls_ = clsB_; } \
        else if (i_ < 1125){ u_ = i_ - 1000; j_ = 4; cls_ = clsI_; } \
        else { u_ = i_ - 1125; j_ = 4; cls_ = clsB_; } \
        int dl_, dd_, dh_; \
        if (u_ < 25){ dd_ = 0; dl_ = u_ / 5; dh_ = u_ - dl_ * 5; } \
        else { int g_ = u_ - 25; dd_ = 1 + g_ / 25; int r2_ = g_ - (dd_ - 1) * 25; \
               dl_ = r2_ / 5; dh_ = r2_ - dl_ * 5; } \
        int m_ = dl_ * 25 + dd_ * 5 + dh_; \
        GLL4(K8G + (size_t)cls_ * 1000 + m_ * 8 + j_, slots + KVQ_OFF + i_); \
      } \
    } \
  } while (0)

#define MITEM { \
    const float* rp = slots + addr; \
    float4 fa = *(const float4*)rp; \
    float4 fb = *(const float4*)(rp + 4); \
    float4 fc = *(const float4*)(rp + 8); \
    float4 kq = *(const float4*)(slots + kvqA); \
    float k4 = slots[kv4A]; \
    fma40(fa, fb, fc, kq, k4, acc); }

#define BITEM(addr_, m_) { \
    const float4* rp4 = (const float4*)(slots + (addr_)); \
    float4 q1 = rp4[0], q2 = rp4[1]; \
    const float* ka = kgB + (m_) * 8; \
    float4 kq = *(const float4*)ka; \
    float k4 = ka[4]; \
    float e0 = wx31 ? q1.w : q1.x; \
    float e1 = wx31 ? q2.x : q1.y; \
    float e2 = wx31 ? q2.y : q1.z; \
    float e3 = wx31 ? q2.z : q1.w; \
    float e4 = wx31 ? q2.w : q2.x; \
    accB = fmaf(kq.x, e0, accB); accB = fmaf(kq.y, e1, accB); \
    accB = fmaf(kq.z, e2, accB); accB = fmaf(kq.w, e3, accB); \
    accB = fmaf(k4,  e4, accB); }

  int cdCur = (dstart == 0) ? 0 : 1;
  LOADKV(cdCur);
  STAGE((dstart + 8)  % 5, dstart - 2);
  STAGE((dstart + 9)  % 5, dstart - 1);
  STAGE((dstart + 10) % 5, dstart);
  STAGE((dstart + 11) % 5, dstart + 1);
  STAGE((dstart + 12) % 5, dstart + 2);
  asm volatile("s_waitcnt vmcnt(0)" ::: "memory");
  __syncthreads();

  for (int s8 = 0; s8 < 8; ++s8){
    int d = dstart + s8;
    int cd = (d == 0) ? 0 : (d == 31) ? 2 : 1;
    if (cd != cdCur){                               // block-uniform, at most once
      cdCur = cd;
      LOADKV(cd);
      asm volatile("s_waitcnt vmcnt(0)" ::: "memory");
      __syncthreads();
    }
    int scomp = (d + 3) % 5;                        // slot of plane d-2 (dd=0)
    const float* kgB = K8G + (size_t)((((cl * 3 + cd) * 3 + chB2) * 3) + cwB) * 1000;

    float acc[8] = {0.f, 0.f, 0.f, 0.f, 0.f, 0.f, 0.f, 0.f};
    float accB = 0.f;

    // ---- phase 1: dd = 0 items (slot scomp, about to be recycled) ----
    {
      int dh = dh0s;
      int addr = scomp * SLOT + (dl0s * 12 + hl + dh) * 36 + oct * 8;
      int kvqA = KVQ_OFF + bndoff4 + sl * 4;
      int kv4A = KVQ_OFF + 1000 + bndoff1 + sl;
      for (int e = sl; e < 25; e += 8){
        MITEM
        addr += 540; dh += 3; kvqA += 32; kv4A += 8;
        if (dh >= 5){ dh -= 5; addr += 252; }
      }
      for (int e1 = subB; e1 < 25; e1 += 16){
        int dlb = (e1 * 205) >> 10, rhb = e1 - dlb * 5;
        BITEM(scomp * SLOT + (dlb * 12 + hlB + rhb) * 36 + wofB, dlb * 25 + rhb)
      }
    }
    __syncthreads();                     // all reads of slot scomp done
    if (s8 < 7) STAGE(scomp, d + 3);     // async: plane d+3 into slot scomp

    // ---- phase 2: dd = 1..4 items (100), hides staging latency ----
    {
      int dl = dl0s, dh = dh0s;
      int si = scomp + 1; if (si >= 5) si -= 5;
      int addr = si * SLOT + (dl * 12 + hl + dh) * 36 + oct * 8;
      int kvqA = KVQ_OFF + bndoff4 + 100 + sl * 4;
      int kv4A = KVQ_OFF + 1000 + bndoff1 + 25 + sl;
      for (int e = sl; e < 100; e += 8){
        MITEM
        addr += 540; dh += 3; dl += 1; kvqA += 32; kv4A += 8;
        if (dh >= 5){ dh -= 5; dl += 1; addr += 252; }
        if (dl >= 5){ dl -= 5; si += 1; if (si >= 5){ si -= 5; addr -= 5 * SLOT; } }
      }
      int r = subB, dd = 1;
      for (int e = subB; e < 100; e += 16){
        int dlb = (r * 205) >> 10, rhb = r - dlb * 5;
        int si2 = scomp + dd; if (si2 >= 5) si2 -= 5;
        BITEM(si2 * SLOT + (dlb * 12 + hlB + rhb) * 36 + wofB, dlb * 25 + dd * 5 + rhb)
        r += 16; if (r >= 25){ r -= 25; dd += 1; }
      }
    }

    // ---- A reduce-scatter butterfly over sl bits (7 shfl) ----
    {
      bool b1 = (sl & 1) != 0;
      float s0 = b1 ? acc[0] : acc[4];
      float s1 = b1 ? acc[1] : acc[5];
      float s2 = b1 ? acc[2] : acc[6];
      float s3 = b1 ? acc[3] : acc[7];
      s0 = __shfl_xor(s0, 8); s1 = __shfl_xor(s1, 8);
      s2 = __shfl_xor(s2, 8); s3 = __shfl_xor(s3, 8);
      float c0 = (b1 ? acc[4] : acc[0]) + s0;
      float c1 = (b1 ? acc[5] : acc[1]) + s1;
      float c2 = (b1 ? acc[6] : acc[2]) + s2;
      float c3 = (b1 ? acc[7] : acc[3]) + s3;
      bool b2 = (sl & 2) != 0;
      float u0 = b2 ? c0 : c2;
      float u1 = b2 ? c1 : c3;
      u0 = __shfl_xor(u0, 16); u1 = __shfl_xor(u1, 16);
      float m0 = (b2 ? c2 : c0) + u0;
      float m1 = (b2 ? c3 : c1) + u1;
      bool b3 = (sl & 4) != 0;
      float v0 = b3 ? m0 : m1;
      v0 = __shfl_xor(v0, 32);
      float r = (b3 ? m1 : m0) + v0;
      int wA = oct * 8 + ((sl & 1) << 2) + (sl & 2) + ((sl >> 2) & 1);
      if (wA != 0 && wA != 31){
        float bvA = bias[l0 * 27 + cd * 9 + chA * 3 + 1];
        xc[(size_t)(l0 * 32 + d) * 1024 + hA * 32 + wA] = r + bvA;
      }
    }

    // ---- B reduction (16 sub-lanes) + store ----
    accB += __shfl_xor(accB, 1);
    accB += __shfl_xor(accB, 2);
    accB += __shfl_xor(accB, 4);
    accB += __shfl_xor(accB, 8);
    if (subB == 0){
      float bvB = bias[l0 * 27 + cd * 9 + chB2 * 3 + cwB];
      xc[(size_t)(l0 * 32 + d) * 1024 + hB * 32 + (wx31 ? 31 : 0)] = accB + bvB;
    }

    asm volatile("s_waitcnt vmcnt(0)" ::: "memory");   // staged plane landed
    __syncthreads();
  }
#undef STG
#undef STAGE
#undef LOADKV
#undef MITEM
#undef BITEM
}

// ============ K3: fused { valp top3 | valq stage1 } + last-block valq stage2 ============
__global__ __launch_bounds__(256) void top_k(float* __restrict__ ws, float* __restrict__ out){
  const float* xc = ws + XC_OFF;
  int bid = blockIdx.x;
  int t = threadIdx.x;

  if (bid < 512){
    // ---- valp: top3 over q per (b,p); wave per row ----
    int wid = bid * 4 + (t >> 6);
    int lane = t & 63;
    int b = wid >> 10, p = wid & 1023;
    const float4* row4 = (const float4*)(xc + (size_t)b * 1048576 + (size_t)p * 1024);
    float a0 = -3.4e38f, a1 = a0, a2 = a0;
    #pragma unroll
    for (int j = 0; j < 4; ++j){
      float4 v = row4[j * 64 + lane];
      ins3(a0, a1, a2, v.x); ins3(a0, a1, a2, v.y);
      ins3(a0, a1, a2, v.z); ins3(a0, a1, a2, v.w);
    }
    for (int off = 32; off; off >>= 1){
      float b0 = __shfl_xor(a0, off), b1 = __shfl_xor(a1, off), b2 = __shfl_xor(a2, off);
      ins3(a0, a1, a2, b0); ins3(a0, a1, a2, b1); ins3(a0, a1, a2, b2);
    }
    if (lane < 3){
      float v = (lane == 0) ? a0 : (lane == 1) ? a1 : a2;
      out[b * 3072 + lane * 1024 + p] = v;
    }
    return;
  }

  // ---- valq stage 1: partial top3 over 32 p's per (b,q) ----
  float* part = ws + PART_OFF;
  int b2 = bid - 512;                        // 256: b(2) x pc(32) x qq(4)
  int qq = b2 & 3, pc = (b2 >> 2) & 31, b = b2 >> 7;
  int q = qq * 256 + t;
  const float* base = xc + (size_t)b * 1048576 + q;
  float a0 = -3.4e38f, a1 = a0, a2 = a0;
  #pragma unroll 4
  for (int i = 0; i < 32; ++i) ins3(a0, a1, a2, base[(size_t)(pc * 32 + i) * 1024]);
  part[(size_t)((b * 32 + pc) * 3 + 0) * 1024 + q] = a0;
  part[(size_t)((b * 32 + pc) * 3 + 1) * 1024 + q] = a1;
  part[(size_t)((b * 32 + pc) * 3 + 2) * 1024 + q] = a2;

  // ---- last arriving block merges (valq stage 2) ----
  __threadfence();
  __shared__ int lastFlag;
  if (t == 0){
    unsigned old = atomicAdd((unsigned*)(ws + CNT_OFF), 1u);
    lastFlag = (old == 255u);
  }
  __syncthreads();
  if (lastFlag){
    __threadfence();
    for (int gid = t; gid < 2048; gid += 256){
      int bb = gid >> 10, qf = gid & 1023;
      float m0 = -3.4e38f, m1 = m0, m2 = m0;
      #pragma unroll 4
      for (int c = 0; c < 96; ++c) ins3(m0, m1, m2, part[(size_t)(bb * 96 + c) * 1024 + qf]);
      out[6144 + bb * 3072 + qf] = m0;
      out[6144 + bb * 3072 + 1024 + qf] = m1;
      out[6144 + bb * 3072 + 2048 + qf] = m2;
    }
    if (t == 0) *(unsigned*)(ws + CNT_OFF) = 0u;
  }
}

extern "C" void kernel_launch(void* const* d_in, const int* in_sizes, int n_in,
                              void* d_out, int out_size, void* d_ws, size_t ws_size,
                              hipStream_t stream){
  const float* xp = (const float*)d_in[0];
  const float* xq = (const float*)d_in[1];
  const float* W1 = (const float*)d_in[2];
  const float* B1 = (const float*)d_in[3];
  const float* W2 = (const float*)d_in[4];
  const float* B2 = (const float*)d_in[5];
  float* out = (float*)d_out;
  float* ws = (float*)d_ws;
  hipLaunchKernelGGL(prep_k, dim3(836),  dim3(256), 0, stream, xp, xq, W1, B1, W2, B2, ws);
  hipLaunchKernelGGL(conv_k, dim3(1024), dim3(256), 0, stream, ws);
  hipLaunchKernelGGL(top_k,  dim3(768),  dim3(256), 0, stream, ws, out);
}

// Round 7
// 268.607 us; speedup vs baseline: 2.1990x; 2.1990x over previous
//
#include <hip/hip_runtime.h>

// ---------------- workspace layout (float offsets) ----------------
#define AFF_OFF   0u         // [2][1024 p][1024 q]
#define XC_OFF    2097152u   // [2][1024 p][1024 q]
#define K8_OFF    4194304u   // Ktab8 [81 cls][125 item][8] (pad cols 5..7 = 0)
#define BIAS_OFF  4275328u   // [32 l][3 cd][3 ch][3 cw]
#define PART_OFF  4276224u   // topq partials [2][32][3][1024]
#define ZP_OFF    4476928u   // zero page (1024 floats)
// total 4477952 floats = 17.9 MB

#define SLOT 2160            // ring-slot stride (floats); 5 slots
#define KVQ_OFF 10800        // kv tables inside LDS: [int f4 500][bnd f4 500][int t4 125][bnd t4 125]

static __device__ __forceinline__ int imax(int a, int b){ return a > b ? a : b; }
static __device__ __forceinline__ int imin(int a, int b){ return a < b ? a : b; }

static __device__ __forceinline__ void ins3(float& a0, float& a1, float& a2, float v){
  if (v > a0){ a2 = a1; a1 = a0; a0 = v; }
  else if (v > a1){ a2 = a1; a1 = v; }
  else if (v > a2){ a2 = v; }
}

static __device__ __forceinline__ void fma40(const float4 fa, const float4 fb, const float4 fc,
                                             const float4 kq, const float k4, float* acc){
  acc[0] = fmaf(kq.x, fa.x, acc[0]); acc[0] = fmaf(kq.y, fa.y, acc[0]);
  acc[0] = fmaf(kq.z, fa.z, acc[0]); acc[0] = fmaf(kq.w, fa.w, acc[0]);
  acc[0] = fmaf(k4,  fb.x, acc[0]);
  acc[1] = fmaf(kq.x, fa.y, acc[1]); acc[1] = fmaf(kq.y, fa.z, acc[1]);
  acc[1] = fmaf(kq.z, fa.w, acc[1]); acc[1] = fmaf(kq.w, fb.x, acc[1]);
  acc[1] = fmaf(k4,  fb.y, acc[1]);
  acc[2] = fmaf(kq.x, fa.z, acc[2]); acc[2] = fmaf(kq.y, fa.w, acc[2]);
  acc[2] = fmaf(kq.z, fb.x, acc[2]); acc[2] = fmaf(kq.w, fb.y, acc[2]);
  acc[2] = fmaf(k4,  fb.z, acc[2]);
  acc[3] = fmaf(kq.x, fa.w, acc[3]); acc[3] = fmaf(kq.y, fb.x, acc[3]);
  acc[3] = fmaf(kq.z, fb.y, acc[3]); acc[3] = fmaf(kq.w, fb.z, acc[3]);
  acc[3] = fmaf(k4,  fb.w, acc[3]);
  acc[4] = fmaf(kq.x, fb.x, acc[4]); acc[4] = fmaf(kq.y, fb.y, acc[4]);
  acc[4] = fmaf(kq.z, fb.z, acc[4]); acc[4] = fmaf(kq.w, fb.w, acc[4]);
  acc[4] = fmaf(k4,  fc.x, acc[4]);
  acc[5] = fmaf(kq.x, fb.y, acc[5]); acc[5] = fmaf(kq.y, fb.z, acc[5]);
  acc[5] = fmaf(kq.z, fb.w, acc[5]); acc[5] = fmaf(kq.w, fc.x, acc[5]);
  acc[5] = fmaf(k4,  fc.y, acc[5]);
  acc[6] = fmaf(kq.x, fb.z, acc[6]); acc[6] = fmaf(kq.y, fb.w, acc[6]);
  acc[6] = fmaf(kq.z, fc.x, acc[6]); acc[6] = fmaf(kq.w, fc.y, acc[6]);
  acc[6] = fmaf(k4,  fc.z, acc[6]);
  acc[7] = fmaf(kq.x, fb.w, acc[7]); acc[7] = fmaf(kq.y, fc.x, acc[7]);
  acc[7] = fmaf(kq.z, fc.y, acc[7]); acc[7] = fmaf(kq.w, fc.z, acc[7]);
  acc[7] = fmaf(k4,  fc.w, acc[7]);
}

#define GLL4(gsrc, ldst) __builtin_amdgcn_global_load_lds( \
    (const __attribute__((address_space(1))) void*)(gsrc), \
    (__attribute__((address_space(3))) void*)(ldst), 4, 0, 0)

// ============ K1: fused { gemm(+norms) | tab } ============
__global__ __launch_bounds__(256) void prep_k(const float* __restrict__ xp,
                                              const float* __restrict__ xq,
                                              const float* __restrict__ W1,
                                              const float* __restrict__ B1,
                                              const float* __restrict__ W2,
                                              const float* __restrict__ B2,
                                              float* __restrict__ ws){
  __shared__ __align__(16) float shbuf[4096];    // gemm: As/Bs dbuf; tab: sW1/sW2
  int bid0 = blockIdx.x;
  int t = threadIdx.x;

  if (bid0 >= 512){
    // ---------------- tab part (324 blocks) ----------------
    float* sW1 = shbuf;
    float* sW2 = shbuf + 1296;
    for (int i = t; i < 1296; i += 256){ sW1[i] = W1[i]; sW2[i] = W2[i]; }
    __syncthreads();
    int tid = (bid0 - 512) * 256 + t;
    if (tid < 50625){
      int c = tid / 625, r = tid % 625;
      int cw = c % 3, ch = (c / 3) % 3, cd = (c / 9) % 3, cl = c / 27;
      int rw = r % 5, rh = (r / 5) % 5, rd = (r / 25) % 5, rl = r / 125;
      int al0 = imax(0, rl - 2), al1 = imin(2, rl);
      if (cl == 0) al0 = imax(al0, 1);
      if (cl == 2) al1 = imin(al1, 1);
      int ad0 = imax(0, rd - 2), ad1 = imin(2, rd);
      if (cd == 0) ad0 = imax(ad0, 1);
      if (cd == 2) ad1 = imin(ad1, 1);
      int ah0 = imax(0, rh - 2), ah1 = imin(2, rh);
      if (ch == 0) ah0 = imax(ah0, 1);
      if (ch == 2) ah1 = imin(ah1, 1);
      int aw0 = imax(0, rw - 2), aw1 = imin(2, rw);
      if (cw == 0) aw0 = imax(aw0, 1);
      if (cw == 2) aw1 = imin(aw1, 1);
      float s = 0.f;
      for (int a = al0; a <= al1; ++a)
        for (int bq = ad0; bq <= ad1; ++bq)
          for (int cq = ah0; cq <= ah1; ++cq)
            for (int dq = aw0; dq <= aw1; ++dq){
              int q2 = ((a * 3 + bq) * 3 + cq) * 3 + dq;
              int q1 = (((rl - a) * 3 + (rd - bq)) * 3 + (rh - cq)) * 3 + (rw - dq);
              for (int co = 0; co < 16; ++co)
                s += sW2[co * 81 + q2] * sW1[co * 81 + q1];
            }
      int item = (r * 205) >> 10;           // r/5
      int j = r - item * 5;
      ws[K8_OFF + (size_t)c * 1000 + item * 8 + j] = s;
    } else if (tid < 51489){
      int t2 = tid - 50625;
      int l = t2 / 27, rest = t2 % 27;
      int cd = rest / 9, ch = (rest / 3) % 3, cw = rest % 3;
      float v = 0.f;
      for (int i = 0; i < 3; ++i){ int y = l + i - 1; if (y >= 0 && y < 32) v += B2[i]; }
      int jlo = (cd == 0) ? 1 : 0, jhi = (cd == 2) ? 1 : 2;
      int klo = (ch == 0) ? 1 : 0, khi = (ch == 2) ? 1 : 2;
      int mlo = (cw == 0) ? 1 : 0, mhi = (cw == 2) ? 1 : 2;
      for (int i = 0; i < 3; ++i){
        int y = l + i - 1; if (y < 0 || y >= 32) continue;
        for (int co = 0; co < 16; ++co){
          float b1e = 0.f;
          for (int i2 = 0; i2 < 3; ++i2){
            int y2 = y + i2 - 1; if (y2 >= 0 && y2 < 32) b1e += B1[i2 * 16 + co];
          }
          float S = 0.f;
          for (int j = jlo; j <= jhi; ++j)
            for (int k = klo; k <= khi; ++k)
              for (int m = mlo; m <= mhi; ++m)
                S += sW2[co * 81 + ((i * 3 + j) * 3 + k) * 3 + m];
          v += b1e * S;
        }
      }
      ws[BIAS_OFF + t2] = v;
    } else if (tid < 52513){
      ws[ZP_OFF + (tid - 51489)] = 0.f;                 // zero page
    } else if (tid < 82888){
      int u = tid - 52513;                              // pad cols 5..7 of Ktab8
      int c = u / 375, r2 = u % 375;
      int item = r2 / 3, j = 5 + r2 % 3;
      ws[K8_OFF + (size_t)c * 1000 + item * 8 + j] = 0.f;
    }
    return;
  }

  // ---------------- gemm part (512 blocks), norms fused ----------------
  int bid = (bid0 & 7) * 64 + (bid0 >> 3);    // XCD swizzle (512 % 8 == 0)
  int qi = bid & 15, pi = (bid >> 4) & 15, b = bid >> 8;
  const float* A = xp + (size_t)b * 262144;   // [c][p]
  const float* B = xq + (size_t)b * 262144;   // [c][q]
  float* C = ws + AFF_OFF + (size_t)b * 1048576;
  int tx = t & 15, ty = t >> 4;
  int row = t >> 4, col = (t & 15) * 4;
  float* As0 = shbuf;            // [16][64]
  float* As1 = shbuf + 1024;
  float* Bs0 = shbuf + 2048;
  float* Bs1 = shbuf + 3072;
  const float* Ag = A + (size_t)row * 1024 + pi * 64 + col;
  const float* Bg = B + (size_t)row * 1024 + qi * 64 + col;
  float4 ra = *(const float4*)Ag;
  float4 rb = *(const float4*)Bg;
  *(float4*)&As0[row * 64 + col] = ra;
  *(float4*)&Bs0[row * 64 + col] = rb;
  __syncthreads();
  float acc[4][4] = {};
  float na[4] = {}, nb[4] = {};
  const float* Asc = As0; const float* Bsc = Bs0;
  float* Asn = As1; float* Bsn = Bs1;
  for (int k0 = 16; k0 <= 256; k0 += 16){
    if (k0 < 256){
      ra = *(const float4*)(Ag + (size_t)k0 * 1024);
      rb = *(const float4*)(Bg + (size_t)k0 * 1024);
    }
    #pragma unroll
    for (int kk = 0; kk < 16; ++kk){
      float4 av = *(const float4*)&Asc[kk * 64 + ty * 4];
      float4 bv = *(const float4*)&Bsc[kk * 64 + tx * 4];
      float a4[4] = {av.x, av.y, av.z, av.w};
      float b4[4] = {bv.x, bv.y, bv.z, bv.w};
      #pragma unroll
      for (int i = 0; i < 4; ++i){
        na[i] = fmaf(a4[i], a4[i], na[i]);
        nb[i] = fmaf(b4[i], b4[i], nb[i]);
        #pragma unroll
        for (int j = 0; j < 4; ++j)
          acc[i][j] = fmaf(a4[i], b4[j], acc[i][j]);
      }
    }
    if (k0 < 256){
      *(float4*)&Asn[row * 64 + col] = ra;
      *(float4*)&Bsn[row * 64 + col] = rb;
      __syncthreads();
      float* tmp;
      tmp = (float*)Asc; Asc = Asn; Asn = tmp;
      tmp = (float*)Bsc; Bsc = Bsn; Bsn = tmp;
    }
  }
  float iva[4], ivb[4];
  #pragma unroll
  for (int i = 0; i < 4; ++i){
    iva[i] = 1.0f / fmaxf(sqrtf(na[i]), 1e-12f);
    ivb[i] = 1.0f / fmaxf(sqrtf(nb[i]), 1e-12f);
  }
  #pragma unroll
  for (int i = 0; i < 4; ++i){
    float4 v = make_float4(acc[i][0] * iva[i] * ivb[0], acc[i][1] * iva[i] * ivb[1],
                           acc[i][2] * iva[i] * ivb[2], acc[i][3] * iva[i] * ivb[3]);
    *(float4*)&C[(size_t)(pi * 64 + ty * 4 + i) * 1024 + qi * 64 + tx * 4] = v;
  }
}

// ============ K2: composed 5^4 conv, d-streamed, split kv tables in LDS ============
__global__ __launch_bounds__(256, 3) void conv_k(float* __restrict__ ws){
  __shared__ __align__(16) float slots[5 * SLOT + 1250];   // 12050 f = 48.2 KB -> 3 blocks/CU

  int bid0 = blockIdx.x;
  int bid = (bid0 & 7) * 128 + (bid0 >> 3);       // XCD swizzle (1024 % 8 == 0)
  int dq = bid & 3, hq = (bid >> 2) & 3, l0 = (bid >> 4) & 31, b = bid >> 9;
  int h0 = hq * 8, dstart = dq * 8;
  int t = threadIdx.x;
  const float* affB = ws + AFF_OFF + (size_t)b * 1048576;
  float* xc = ws + XC_OFF + (size_t)b * 1048576;
  const float* K8G = ws + K8_OFF;
  const float* bias = ws + BIAS_OFF;
  const float* zp = ws + ZP_OFF;

  int cl = (l0 == 0) ? 0 : (l0 == 31) ? 2 : 1;
  int chB = (hq == 0) ? 0 : (hq == 3) ? 2 : 1;    // boundary-row h class (1 if none)

  // A-phase lane constants: t = wv(2b) | sl(3b) | hsel(1b) | oct(2b)
  int wv = t >> 6, u3 = t & 7;
  int oct = u3 & 3, hsel = u3 >> 2, hl = wv * 2 + hsel;
  int hA = h0 + hl;
  int chA = (hA == 0) ? 0 : (hA == 31) ? 2 : 1;
  int sl = (t >> 3) & 7;
  int dl0s = (sl >= 5) ? 1 : 0;
  int dh0s = sl - 5 * dl0s;
  bool isBnd = (hq == 0 && hl == 0) || (hq == 3 && hl == 7);
  int bndoff4 = isBnd ? 500 : 0;
  int bndoff1 = isBnd ? 125 : 0;

  // B-phase lane constants
  int outB = t >> 4, subB = t & 15;
  int hlB = outB >> 1, wx31 = outB & 1;
  int hB = h0 + hlB;
  int chB2 = (hB == 0) ? 0 : (hB == 31) ? 2 : 1;
  int cwB = wx31 ? 2 : 0;
  int wofB = wx31 ? 28 : 0;

  // staging global offsets (9 rounds x 256 lanes = 2160 floats/plane)
  int o0, o1, o2, o3, o4, o5, o6, o7, o8;
#define PRE(r) { int flat = (r)*256 + t; \
    int wi = flat % 36; int rest = flat / 36; int hi = rest % 12; int dl2 = rest / 12; \
    int lp_ = l0 + dl2 - 2, hp_ = h0 + hi - 2, wp_ = wi - 2; \
    bool ok = ((unsigned)lp_ < 32u) && ((unsigned)hp_ < 32u) && ((unsigned)wp_ < 32u); \
    o##r = ok ? (lp_ * 32768 + hp_ * 32 + wp_) : -1; }
  PRE(0) PRE(1) PRE(2) PRE(3) PRE(4) PRE(5) PRE(6) PRE(7) PRE(8)
#undef PRE

#define STG(r, sp_) { const float* s_ = (pOK_ && o##r >= 0) ? (affB + o##r + dpo_) : zp; \
    GLL4(s_, sp_ + (r)*256 + t); }
#define STAGE(si_, dpv_) do { \
    int dp_ = (dpv_); bool pOK_ = ((unsigned)dp_ < 32u); int dpo_ = dp_ * 1024; \
    float* sp_ = slots + (si_) * SLOT; \
    STG(0, sp_) STG(1, sp_) STG(2, sp_) STG(3, sp_) \
    STG(4, sp_) STG(5, sp_) STG(6, sp_) STG(7, sp_) \
    if (t < 112) sp_[2048 + t] = (pOK_ && o8 >= 0) ? affB[o8 + dpo_] : 0.f; \
  } while (0)

  // kv tables: entries in traversal order u=0..124 (u<25: dd=0; u>=25: dd=1+..)
#define LOADKV(cdv_) do { int cd_ = (cdv_); \
    int clsI_ = ((cl * 3 + cd_) * 3 + 1) * 3 + 1; \
    int clsB_ = ((cl * 3 + cd_) * 3 + chB) * 3 + 1; \
    for (int r_ = 0; r_ < 5; ++r_){ \
      int i_ = r_ * 256 + t; \
      if (i_ < 1250){ \
        int u_, j_, cls_; \
        if (i_ < 500){ u_ = i_ >> 2; j_ = i_ & 3; cls_ = clsI_; } \
        else if (i_ < 1000){ u_ = (i_ - 500) >> 2; j_ = i_ & 3; cls_ = clsB_; } \
        else if (i_ < 1125){ u_ = i_ - 1000; j_ = 4; cls_ = clsI_; } \
        else { u_ = i_ - 1125; j_ = 4; cls_ = clsB_; } \
        int dl_, dd_, dh_; \
        if (u_ < 25){ dd_ = 0; dl_ = u_ / 5; dh_ = u_ - dl_ * 5; } \
        else { int g_ = u_ - 25; dd_ = 1 + g_ / 25; int r2_ = g_ - (dd_ - 1) * 25; \
               dl_ = r2_ / 5; dh_ = r2_ - dl_ * 5; } \
        int m_ = dl_ * 25 + dd_ * 5 + dh_; \
        GLL4(K8G + (size_t)cls_ * 1000 + m_ * 8 + j_, slots + KVQ_OFF + i_); \
      } \
    } \
  } while (0)

#define MITEM { \
    const float* rp = slots + addr; \
    float4 fa = *(const float4*)rp; \
    float4 fb = *(const float4*)(rp + 4); \
    float4 fc = *(const float4*)(rp + 8); \
    float4 kq = *(const float4*)(slots + kvqA); \
    float k4 = slots[kv4A]; \
    fma40(fa, fb, fc, kq, k4, acc); }

#define BITEM(addr_, m_) { \
    const float4* rp4 = (const float4*)(slots + (addr_)); \
    float4 q1 = rp4[0], q2 = rp4[1]; \
    const float* ka = kgB + (m_) * 8; \
    float4 kq = *(const float4*)ka; \
    float k4 = ka[4]; \
    float e0 = wx31 ? q1.w : q1.x; \
    float e1 = wx31 ? q2.x : q1.y; \
    float e2 = wx31 ? q2.y : q1.z; \
    float e3 = wx31 ? q2.z : q1.w; \
    float e4 = wx31 ? q2.w : q2.x; \
    accB = fmaf(kq.x, e0, accB); accB = fmaf(kq.y, e1, accB); \
    accB = fmaf(kq.z, e2, accB); accB = fmaf(kq.w, e3, accB); \
    accB = fmaf(k4,  e4, accB); }

  int cdCur = (dstart == 0) ? 0 : 1;
  LOADKV(cdCur);
  STAGE((dstart + 8)  % 5, dstart - 2);
  STAGE((dstart + 9)  % 5, dstart - 1);
  STAGE((dstart + 10) % 5, dstart);
  STAGE((dstart + 11) % 5, dstart + 1);
  STAGE((dstart + 12) % 5, dstart + 2);
  asm volatile("s_waitcnt vmcnt(0)" ::: "memory");
  __syncthreads();

  for (int s8 = 0; s8 < 8; ++s8){
    int d = dstart + s8;
    int cd = (d == 0) ? 0 : (d == 31) ? 2 : 1;
    if (cd != cdCur){                               // block-uniform, at most once
      cdCur = cd;
      LOADKV(cd);
      asm volatile("s_waitcnt vmcnt(0)" ::: "memory");
      __syncthreads();
    }
    int scomp = (d + 3) % 5;                        // slot of plane d-2 (dd=0)
    const float* kgB = K8G + (size_t)((((cl * 3 + cd) * 3 + chB2) * 3) + cwB) * 1000;

    float acc[8] = {0.f, 0.f, 0.f, 0.f, 0.f, 0.f, 0.f, 0.f};
    float accB = 0.f;

    // ---- phase 1: dd = 0 items (slot scomp, about to be recycled) ----
    {
      int dh = dh0s;
      int addr = scomp * SLOT + (dl0s * 12 + hl + dh) * 36 + oct * 8;
      int kvqA = KVQ_OFF + bndoff4 + sl * 4;
      int kv4A = KVQ_OFF + 1000 + bndoff1 + sl;
      for (int e = sl; e < 25; e += 8){
        MITEM
        addr += 540; dh += 3; kvqA += 32; kv4A += 8;
        if (dh >= 5){ dh -= 5; addr += 252; }
      }
      for (int e1 = subB; e1 < 25; e1 += 16){
        int dlb = (e1 * 205) >> 10, rhb = e1 - dlb * 5;
        BITEM(scomp * SLOT + (dlb * 12 + hlB + rhb) * 36 + wofB, dlb * 25 + rhb)
      }
    }
    __syncthreads();                     // all reads of slot scomp done
    if (s8 < 7) STAGE(scomp, d + 3);     // async: plane d+3 into slot scomp

    // ---- phase 2: dd = 1..4 items (100), hides staging latency ----
    {
      int dl = dl0s, dh = dh0s;
      int si = scomp + 1; if (si >= 5) si -= 5;
      int addr = si * SLOT + (dl * 12 + hl + dh) * 36 + oct * 8;
      int kvqA = KVQ_OFF + bndoff4 + 100 + sl * 4;
      int kv4A = KVQ_OFF + 1000 + bndoff1 + 25 + sl;
      for (int e = sl; e < 100; e += 8){
        MITEM
        addr += 540; dh += 3; dl += 1; kvqA += 32; kv4A += 8;
        if (dh >= 5){ dh -= 5; dl += 1; addr += 252; }
        if (dl >= 5){ dl -= 5; si += 1; if (si >= 5){ si -= 5; addr -= 5 * SLOT; } }
      }
      int r = subB, dd = 1;
      for (int e = subB; e < 100; e += 16){
        int dlb = (r * 205) >> 10, rhb = r - dlb * 5;
        int si2 = scomp + dd; if (si2 >= 5) si2 -= 5;
        BITEM(si2 * SLOT + (dlb * 12 + hlB + rhb) * 36 + wofB, dlb * 25 + dd * 5 + rhb)
        r += 16; if (r >= 25){ r -= 25; dd += 1; }
      }
    }

    // ---- A reduce-scatter butterfly over sl bits (7 shfl) ----
    {
      bool b1 = (sl & 1) != 0;
      float s0 = b1 ? acc[0] : acc[4];
      float s1 = b1 ? acc[1] : acc[5];
      float s2 = b1 ? acc[2] : acc[6];
      float s3 = b1 ? acc[3] : acc[7];
      s0 = __shfl_xor(s0, 8); s1 = __shfl_xor(s1, 8);
      s2 = __shfl_xor(s2, 8); s3 = __shfl_xor(s3, 8);
      float c0 = (b1 ? acc[4] : acc[0]) + s0;
      float c1 = (b1 ? acc[5] : acc[1]) + s1;
      float c2 = (b1 ? acc[6] : acc[2]) + s2;
      float c3 = (b1 ? acc[7] : acc[3]) + s3;
      bool b2 = (sl & 2) != 0;
      float u0 = b2 ? c0 : c2;
      float u1 = b2 ? c1 : c3;
      u0 = __shfl_xor(u0, 16); u1 = __shfl_xor(u1, 16);
      float m0 = (b2 ? c2 : c0) + u0;
      float m1 = (b2 ? c3 : c1) + u1;
      bool b3 = (sl & 4) != 0;
      float v0 = b3 ? m0 : m1;
      v0 = __shfl_xor(v0, 32);
      float r = (b3 ? m1 : m0) + v0;
      int wA = oct * 8 + ((sl & 1) << 2) + (sl & 2) + ((sl >> 2) & 1);
      if (wA != 0 && wA != 31){
        float bvA = bias[l0 * 27 + cd * 9 + chA * 3 + 1];
        xc[(size_t)(l0 * 32 + d) * 1024 + hA * 32 + wA] = r + bvA;
      }
    }

    // ---- B reduction (16 sub-lanes) + store ----
    accB += __shfl_xor(accB, 1);
    accB += __shfl_xor(accB, 2);
    accB += __shfl_xor(accB, 4);
    accB += __shfl_xor(accB, 8);
    if (subB == 0){
      float bvB = bias[l0 * 27 + cd * 9 + chB2 * 3 + cwB];
      xc[(size_t)(l0 * 32 + d) * 1024 + hB * 32 + (wx31 ? 31 : 0)] = accB + bvB;
    }

    asm volatile("s_waitcnt vmcnt(0)" ::: "memory");   // staged plane landed
    __syncthreads();
  }
#undef STG
#undef STAGE
#undef LOADKV
#undef MITEM
#undef BITEM
}

// ============ K3: fused { valp top3 | valq stage1 } (no atomics) ============
__global__ __launch_bounds__(256) void top1_k(const float* __restrict__ ws, float* __restrict__ out){
  const float* xc = ws + XC_OFF;
  int bid = blockIdx.x;
  int t = threadIdx.x;

  if (bid < 512){
    // ---- valp: top3 over q per (b,p); wave per row ----
    int wid = bid * 4 + (t >> 6);
    int lane = t & 63;
    int b = wid >> 10, p = wid & 1023;
    const float4* row4 = (const float4*)(xc + (size_t)b * 1048576 + (size_t)p * 1024);
    float a0 = -3.4e38f, a1 = a0, a2 = a0;
    #pragma unroll
    for (int j = 0; j < 4; ++j){
      float4 v = row4[j * 64 + lane];
      ins3(a0, a1, a2, v.x); ins3(a0, a1, a2, v.y);
      ins3(a0, a1, a2, v.z); ins3(a0, a1, a2, v.w);
    }
    for (int off = 32; off; off >>= 1){
      float b0 = __shfl_xor(a0, off), b1 = __shfl_xor(a1, off), b2 = __shfl_xor(a2, off);
      ins3(a0, a1, a2, b0); ins3(a0, a1, a2, b1); ins3(a0, a1, a2, b2);
    }
    if (lane < 3){
      float v = (lane == 0) ? a0 : (lane == 1) ? a1 : a2;
      out[b * 3072 + lane * 1024 + p] = v;
    }
    return;
  }

  // ---- valq stage 1: partial top3 over 32 p's per (b,q) ----
  float* part = (float*)ws + PART_OFF;
  int b2 = bid - 512;                        // 256: b(2) x pc(32) x qq(4)
  int qq = b2 & 3, pc = (b2 >> 2) & 31, b = b2 >> 7;
  int q = qq * 256 + t;
  const float* base = xc + (size_t)b * 1048576 + q;
  float a0 = -3.4e38f, a1 = a0, a2 = a0;
  #pragma unroll 4
  for (int i = 0; i < 32; ++i) ins3(a0, a1, a2, base[(size_t)(pc * 32 + i) * 1024]);
  part[(size_t)((b * 32 + pc) * 3 + 0) * 1024 + q] = a0;
  part[(size_t)((b * 32 + pc) * 3 + 1) * 1024 + q] = a1;
  part[(size_t)((b * 32 + pc) * 3 + 2) * 1024 + q] = a2;
}

// ============ K4: valq stage 2 (tiny) ============
__global__ __launch_bounds__(256) void top2_k(const float* __restrict__ ws, float* __restrict__ out){
  const float* part = ws + PART_OFF;
  int gid = blockIdx.x * 256 + threadIdx.x;   // 2048
  int b = gid >> 10, q = gid & 1023;
  float a0 = -3.4e38f, a1 = a0, a2 = a0;
  #pragma unroll 4
  for (int c = 0; c < 96; ++c) ins3(a0, a1, a2, part[(size_t)(b * 96 + c) * 1024 + q]);
  out[6144 + b * 3072 + q] = a0;
  out[6144 + b * 3072 + 1024 + q] = a1;
  out[6144 + b * 3072 + 2048 + q] = a2;
}

extern "C" void kernel_launch(void* const* d_in, const int* in_sizes, int n_in,
                              void* d_out, int out_size, void* d_ws, size_t ws_size,
                              hipStream_t stream){
  const float* xp = (const float*)d_in[0];
  const float* xq = (const float*)d_in[1];
  const float* W1 = (const float*)d_in[2];
  const float* B1 = (const float*)d_in[3];
  const float* W2 = (const float*)d_in[4];
  const float* B2 = (const float*)d_in[5];
  float* out = (float*)d_out;
  float* ws = (float*)d_ws;
  hipLaunchKernelGGL(prep_k, dim3(836),  dim3(256), 0, stream, xp, xq, W1, B1, W2, B2, ws);
  hipLaunchKernelGGL(conv_k, dim3(1024), dim3(256), 0, stream, ws);
  hipLaunchKernelGGL(top1_k, dim3(768),  dim3(256), 0, stream, ws, out);
  hipLaunchKernelGGL(top2_k, dim3(8),    dim3(256), 0, stream, ws, out);
}